// Round 1
// baseline (128.734 us; speedup 1.0000x reference)
//
#include <hip/hip_runtime.h>

// SwarmNet: N=128 samples, T=100, D=4, H=32, Tp=94.
// Kernel 1: per-sample conv stack (3 VALID convs, k=3) + ej/ei projections.
// Kernel 2: per-(t, i-slice) pairwise aggregation + Wa/Wu/Wd matmuls + residual.

#define NN 128
#define TT 100
#define TP 94
#define HH 32

__global__ __launch_bounds__(256) void k_conv(
    const float* __restrict__ x,
    const float* __restrict__ w1, const float* __restrict__ b1,
    const float* __restrict__ w2, const float* __restrict__ b2,
    const float* __restrict__ w3, const float* __restrict__ b3,
    const float* __restrict__ We,
    float* __restrict__ h_g, float* __restrict__ ej_g, float* __restrict__ ei_g)
{
    __shared__ float sx[4][100];
    __shared__ float s1[16][98];
    __shared__ float s2[32][96];
    __shared__ float s3[32][94];
    __shared__ float sw1[192], sw2[1536], sw3[3072], sWe[2048];
    __shared__ float sb1[16], sb2[32], sb3[32];

    const int n   = blockIdx.x;
    const int tid = threadIdx.x;

    for (int idx = tid; idx < 400; idx += 256) {
        int t = idx >> 2, d = idx & 3;
        sx[d][t] = x[n * 400 + idx];
    }
    for (int idx = tid; idx < 192;  idx += 256) sw1[idx] = w1[idx];
    for (int idx = tid; idx < 1536; idx += 256) sw2[idx] = w2[idx];
    for (int idx = tid; idx < 3072; idx += 256) sw3[idx] = w3[idx];
    for (int idx = tid; idx < 2048; idx += 256) sWe[idx] = We[idx];
    if (tid < 16) sb1[tid] = b1[tid];
    else if (tid < 48) sb2[tid - 16] = b2[tid - 16];
    else if (tid < 80) sb3[tid - 48] = b3[tid - 48];
    __syncthreads();

    // conv1: (4,100) -> (16,98)
    for (int idx = tid; idx < 16 * 98; idx += 256) {
        int o = idx / 98, t = idx % 98;
        float acc = sb1[o];
        #pragma unroll
        for (int i = 0; i < 4; ++i)
            #pragma unroll
            for (int k = 0; k < 3; ++k)
                acc += sx[i][t + k] * sw1[o * 12 + i * 3 + k];
        s1[o][t] = fmaxf(acc, 0.f);
    }
    __syncthreads();

    // conv2: (16,98) -> (32,96)
    for (int idx = tid; idx < 32 * 96; idx += 256) {
        int o = idx / 96, t = idx % 96;
        float acc = sb2[o];
        #pragma unroll
        for (int i = 0; i < 16; ++i)
            #pragma unroll
            for (int k = 0; k < 3; ++k)
                acc += s1[i][t + k] * sw2[o * 48 + i * 3 + k];
        s2[o][t] = fmaxf(acc, 0.f);
    }
    __syncthreads();

    // conv3: (32,96) -> (32,94), write h to global as [t][n][c]
    for (int idx = tid; idx < 32 * 94; idx += 256) {
        int o = idx / 94, t = idx % 94;
        float acc = sb3[o];
        #pragma unroll
        for (int i = 0; i < 32; ++i)
            #pragma unroll
            for (int k = 0; k < 3; ++k)
                acc += s2[i][t + k] * sw3[o * 96 + i * 3 + k];
        float v = fmaxf(acc, 0.f);
        s3[o][t] = v;
        h_g[(t * NN + n) * HH + o] = v;
    }
    __syncthreads();

    // ej = h @ We[:32], ei = h @ We[32:], layout [t][n][d]
    for (int idx = tid; idx < TP * HH; idx += 256) {
        int t = idx >> 5, d = idx & 31;
        float aj = 0.f, ai = 0.f;
        #pragma unroll
        for (int c = 0; c < 32; ++c) {
            float hv = s3[c][t];
            aj += hv * sWe[c * 32 + d];
            ai += hv * sWe[(32 + c) * 32 + d];
        }
        ej_g[(t * NN + n) * HH + d] = aj;
        ei_g[(t * NN + n) * HH + d] = ai;
    }
}

__global__ __launch_bounds__(256) void k_agg(
    const float* __restrict__ x,
    const float* __restrict__ h_g, const float* __restrict__ ej_g,
    const float* __restrict__ ei_g,
    const float* __restrict__ be, const float* __restrict__ Wa,
    const float* __restrict__ ba, const float* __restrict__ Wu,
    const float* __restrict__ bu, const float* __restrict__ Wd,
    const float* __restrict__ bd, float* __restrict__ out)
{
    const int t  = blockIdx.x;  // 0..93
    const int ib = blockIdx.y;  // 0..3 (i-slice of 32 rows)
    const int tid = threadIdx.x;

    __shared__ float sej[NN * HH];      // ej[t, all j, d]
    __shared__ float sei[32 * HH];
    __shared__ float sh[32 * HH];
    __shared__ float sagg[32 * HH];
    __shared__ float sagg2[32 * HH];
    __shared__ float supd[32 * HH];
    __shared__ float sWa[1024], sWu[2048], sWd[128];
    __shared__ float sbe[32], sba[32], sbu[32], sbd[4];

    const float* ejt = ej_g + t * NN * HH;
    for (int idx = tid; idx < NN * HH; idx += 256) sej[idx] = ejt[idx];
    const float* eit = ei_g + (t * NN + ib * 32) * HH;
    const float* ht  = h_g  + (t * NN + ib * 32) * HH;
    for (int idx = tid; idx < 32 * HH; idx += 256) { sei[idx] = eit[idx]; sh[idx] = ht[idx]; }
    for (int idx = tid; idx < 1024; idx += 256) sWa[idx] = Wa[idx];
    for (int idx = tid; idx < 2048; idx += 256) sWu[idx] = Wu[idx];
    if (tid < 128) sWd[tid] = Wd[tid];
    if (tid < 32) { sbe[tid] = be[tid]; sba[tid] = ba[tid]; sbu[tid] = bu[tid]; }
    if (tid >= 32 && tid < 36) sbd[tid - 32] = bd[tid - 32];
    __syncthreads();

    const int d  = tid & 31;
    const int i0 = tid >> 5;  // 0..7; each thread owns i = i0 + u*8, u<4

    // agg[i,d] = sum_j relu(ej[j,d] + ei[i,d] + be[d]) - relu(ej[gi,d] + ei[i,d] + be[d])
    {
        float c[4], acc[4];
        #pragma unroll
        for (int u = 0; u < 4; ++u) {
            int i = i0 + u * 8;
            c[u] = sei[i * HH + d] + sbe[d];
            acc[u] = -fmaxf(sej[(ib * 32 + i) * HH + d] + c[u], 0.f);
        }
        for (int j = 0; j < NN; ++j) {
            float v = sej[j * HH + d];   // broadcast across lanes sharing d
            #pragma unroll
            for (int u = 0; u < 4; ++u)
                acc[u] += fmaxf(v + c[u], 0.f);
        }
        #pragma unroll
        for (int u = 0; u < 4; ++u)
            sagg[(i0 + u * 8) * HH + d] = acc[u];
    }
    __syncthreads();

    // agg2 = relu(agg @ Wa + ba)
    {
        #pragma unroll
        for (int u = 0; u < 4; ++u) {
            int i = i0 + u * 8;
            float a = sba[d];
            #pragma unroll
            for (int c = 0; c < 32; ++c)
                a += sagg[i * HH + c] * sWa[c * 32 + d];
            sagg2[i * HH + d] = fmaxf(a, 0.f);
        }
    }
    __syncthreads();

    // upd = relu(h @ Wu[:32] + agg2 @ Wu[32:] + bu)
    {
        #pragma unroll
        for (int u = 0; u < 4; ++u) {
            int i = i0 + u * 8;
            float a = sbu[d];
            #pragma unroll
            for (int c = 0; c < 32; ++c)
                a += sh[i * HH + c] * sWu[c * 32 + d]
                   + sagg2[i * HH + c] * sWu[(32 + c) * 32 + d];
            supd[i * HH + d] = fmaxf(a, 0.f);
        }
    }
    __syncthreads();

    // dec = upd @ Wd + bd; out[n, t, d4] = x[n, 6+t, d4] + dec
    if (tid < 128) {
        int i = tid >> 2, d4 = tid & 3;
        int n = ib * 32 + i;
        float a = sbd[d4];
        #pragma unroll
        for (int c = 0; c < 32; ++c)
            a += supd[i * HH + c] * sWd[c * 4 + d4];
        out[n * (TP * 4) + t * 4 + d4] = x[n * (TT * 4) + (6 + t) * 4 + d4] + a;
    }
}

extern "C" void kernel_launch(void* const* d_in, const int* in_sizes, int n_in,
                              void* d_out, int out_size, void* d_ws, size_t ws_size,
                              hipStream_t stream) {
    const float* x  = (const float*)d_in[0];
    const float* w1 = (const float*)d_in[1];
    const float* b1 = (const float*)d_in[2];
    const float* w2 = (const float*)d_in[3];
    const float* b2 = (const float*)d_in[4];
    const float* w3 = (const float*)d_in[5];
    const float* b3 = (const float*)d_in[6];
    const float* We = (const float*)d_in[7];
    const float* be = (const float*)d_in[8];
    const float* Wa = (const float*)d_in[9];
    const float* ba = (const float*)d_in[10];
    const float* Wu = (const float*)d_in[11];
    const float* bu = (const float*)d_in[12];
    const float* Wd = (const float*)d_in[13];
    const float* bd = (const float*)d_in[14];

    float* ws   = (float*)d_ws;
    float* h_g  = ws;                      // 94*128*32
    float* ej_g = ws + TP * NN * HH;       // 94*128*32
    float* ei_g = ws + 2 * TP * NN * HH;   // 94*128*32

    k_conv<<<NN, 256, 0, stream>>>(x, w1, b1, w2, b2, w3, b3, We, h_g, ej_g, ei_g);
    k_agg<<<dim3(TP, 4), 256, 0, stream>>>(x, h_g, ej_g, ei_g,
                                           be, Wa, ba, Wu, bu, Wd, bd,
                                           (float*)d_out);
}

// Round 2
// 102.779 us; speedup vs baseline: 1.2525x; 1.2525x over previous
//
#include <hip/hip_runtime.h>

// SwarmNet: N=128 samples(=agents), T=100, D=4, H=32, Tp=94.
// k_conv: grid (128, 2). Block = (sample n, t-half). Computes 3 conv stages in
//   LDS with register-tiled threads (o, 8-t tile), b128 activation reads,
//   weights straight from global (L1-hot). Emits h, ej, ei in [t][n][c] layout.
// k_agg: grid (94, 4). Pairwise relu-sum aggregation + Wa/Wu/Wd matmuls + residual.

#define NN 128
#define TT 100
#define TP 94
#define HH 32

__global__ __launch_bounds__(256) void k_conv(
    const float* __restrict__ x,
    const float* __restrict__ w1, const float* __restrict__ b1,
    const float* __restrict__ w2, const float* __restrict__ b2,
    const float* __restrict__ w3, const float* __restrict__ b3,
    const float* __restrict__ We,
    float* __restrict__ h_g, float* __restrict__ ej_g, float* __restrict__ ei_g)
{
    __shared__ float sx[4][72];    // x cols [t0g, t0g+54), zero-padded to 72
    __shared__ float s1[16][68];   // conv1 out (valid t<52)
    __shared__ float s2[32][64];   // conv2 out (valid t<50)
    __shared__ float s3[32][48];   // conv3 out (valid t<48)

    const int n    = blockIdx.x;
    const int half = blockIdx.y;
    const int t0g  = half * 46;    // out t-range [t0g, t0g+48); halves overlap at 46,47
    const int tid  = threadIdx.x;

    // stage x: 54 float4 columns; zero-fill pad columns
    if (tid < 72) {
        float4 v = make_float4(0.f, 0.f, 0.f, 0.f);
        if (tid < 54) v = ((const float4*)x)[n * TT + t0g + tid];
        sx[0][tid] = v.x; sx[1][tid] = v.y; sx[2][tid] = v.z; sx[3][tid] = v.w;
    }
    __syncthreads();

    // conv1: (4,·) -> (16,·), 16*68 outputs, flat
    for (int idx = tid; idx < 16 * 68; idx += 256) {
        int o = idx / 68, t = idx - o * 68;
        float acc = b1[o];
        #pragma unroll
        for (int i = 0; i < 4; ++i)
            #pragma unroll
            for (int k = 0; k < 3; ++k)
                acc += sx[i][t + k] * w1[o * 12 + i * 3 + k];
        s1[o][t] = fmaxf(acc, 0.f);
    }
    __syncthreads();

    // conv2: (16,·) -> (32,·). thread = (o=tid&31, seg=tid>>5), 8 t each, t0=seg*8
    {
        const int o = tid & 31, seg = tid >> 5;
        const int t0 = seg * 8;
        float acc[8];
        float bv = b2[o];
        #pragma unroll
        for (int u = 0; u < 8; ++u) acc[u] = bv;
        #pragma unroll
        for (int i = 0; i < 16; ++i) {
            float4 f0 = *(const float4*)&s1[i][t0];
            float4 f1 = *(const float4*)&s1[i][t0 + 4];
            float4 f2 = *(const float4*)&s1[i][t0 + 8];
            float a[12] = {f0.x, f0.y, f0.z, f0.w, f1.x, f1.y, f1.z, f1.w,
                           f2.x, f2.y, f2.z, f2.w};
            float W0 = w2[o * 48 + i * 3 + 0];
            float W1 = w2[o * 48 + i * 3 + 1];
            float W2 = w2[o * 48 + i * 3 + 2];
            #pragma unroll
            for (int u = 0; u < 8; ++u)
                acc[u] += a[u] * W0 + a[u + 1] * W1 + a[u + 2] * W2;
        }
        #pragma unroll
        for (int u = 0; u < 8; ++u) s2[o][t0 + u] = fmaxf(acc[u], 0.f);
    }
    __syncthreads();

    // conv3: (32,·) -> (32,48). thread = (o=tid&31, seg=tid>>5<6), 8 t each
    {
        const int o = tid & 31, seg = tid >> 5;
        if (seg < 6) {
            const int t0 = seg * 8;
            float acc[8];
            float bv = b3[o];
            #pragma unroll
            for (int u = 0; u < 8; ++u) acc[u] = bv;
            #pragma unroll
            for (int i = 0; i < 32; ++i) {
                float4 f0 = *(const float4*)&s2[i][t0];
                float4 f1 = *(const float4*)&s2[i][t0 + 4];
                float4 f2 = *(const float4*)&s2[i][t0 + 8];
                float a[12] = {f0.x, f0.y, f0.z, f0.w, f1.x, f1.y, f1.z, f1.w,
                               f2.x, f2.y, f2.z, f2.w};
                float W0 = w3[o * 96 + i * 3 + 0];
                float W1 = w3[o * 96 + i * 3 + 1];
                float W2 = w3[o * 96 + i * 3 + 2];
                #pragma unroll
                for (int u = 0; u < 8; ++u)
                    acc[u] += a[u] * W0 + a[u + 1] * W1 + a[u + 2] * W2;
            }
            #pragma unroll
            for (int u = 0; u < 8; ++u) s3[o][t0 + u] = fmaxf(acc[u], 0.f);
        }
    }
    __syncthreads();

    // h store: coalesced flat copy s3 -> h_g[t][n][o]
    for (int idx = tid; idx < 48 * 32; idx += 256) {
        int tl = idx >> 5, o = idx & 31;
        h_g[((t0g + tl) * NN + n) * HH + o] = s3[o][tl];
    }

    // proj: ej = h@We[:32], ei = h@We[32:]. thread = (d=tid&31, seg=tid>>5<6), 8 t
    {
        const int d = tid & 31, seg = tid >> 5;
        if (seg < 6) {
            const int t0 = seg * 8;
            float aj[8], ai[8];
            #pragma unroll
            for (int u = 0; u < 8; ++u) { aj[u] = 0.f; ai[u] = 0.f; }
            #pragma unroll
            for (int c = 0; c < 32; ++c) {
                float4 f0 = *(const float4*)&s3[c][t0];
                float4 f1 = *(const float4*)&s3[c][t0 + 4];
                float hv[8] = {f0.x, f0.y, f0.z, f0.w, f1.x, f1.y, f1.z, f1.w};
                float wj = We[c * 32 + d];
                float wi = We[(32 + c) * 32 + d];
                #pragma unroll
                for (int u = 0; u < 8; ++u) {
                    aj[u] += hv[u] * wj;
                    ai[u] += hv[u] * wi;
                }
            }
            #pragma unroll
            for (int u = 0; u < 8; ++u) {
                int tg = t0g + t0 + u;
                ej_g[(tg * NN + n) * HH + d] = aj[u];
                ei_g[(tg * NN + n) * HH + d] = ai[u];
            }
        }
    }
}

__global__ __launch_bounds__(256) void k_agg(
    const float* __restrict__ x,
    const float* __restrict__ h_g, const float* __restrict__ ej_g,
    const float* __restrict__ ei_g,
    const float* __restrict__ be, const float* __restrict__ Wa,
    const float* __restrict__ ba, const float* __restrict__ Wu,
    const float* __restrict__ bu, const float* __restrict__ Wd,
    const float* __restrict__ bd, float* __restrict__ out)
{
    const int t  = blockIdx.x;  // 0..93
    const int ib = blockIdx.y;  // 0..3 (i-slice of 32 agents)
    const int tid = threadIdx.x;

    __shared__ float sej[NN * HH];
    __shared__ float sei[32 * HH];
    __shared__ float sh[32 * HH];
    __shared__ float sagg[32 * HH];
    __shared__ float sagg2[32 * HH];
    __shared__ float supd[32 * HH];

    // stage ej[t,:,:] (16 KB) + ei/h slices, vectorized
    {
        const float4* ej4 = (const float4*)(ej_g + t * NN * HH);
        float4* s4 = (float4*)sej;
        #pragma unroll
        for (int u = 0; u < 4; ++u) s4[tid + 256 * u] = ej4[tid + 256 * u];
        const float4* ei4 = (const float4*)(ei_g + (t * NN + ib * 32) * HH);
        const float4* h4  = (const float4*)(h_g  + (t * NN + ib * 32) * HH);
        ((float4*)sei)[tid] = ei4[tid];
        ((float4*)sh)[tid]  = h4[tid];
    }
    __syncthreads();

    const int d  = tid & 31;
    const int i0 = tid >> 5;  // 0..7; thread owns i = i0 + 8u, u<4

    // agg[i,d] = sum_j relu(ej[j,d] + ei[i,d] + be[d]) - diag
    {
        float bev = be[d];
        float c[4], acc[4];
        #pragma unroll
        for (int u = 0; u < 4; ++u) {
            int i = i0 + u * 8;
            c[u] = sei[i * HH + d] + bev;
            acc[u] = -fmaxf(sej[(ib * 32 + i) * HH + d] + c[u], 0.f);
        }
        #pragma unroll 8
        for (int j = 0; j < NN; ++j) {
            float v = sej[j * HH + d];
            #pragma unroll
            for (int u = 0; u < 4; ++u)
                acc[u] += fmaxf(v + c[u], 0.f);
        }
        #pragma unroll
        for (int u = 0; u < 4; ++u)
            sagg[(i0 + u * 8) * HH + d] = acc[u];
    }
    __syncthreads();

    // agg2 = relu(agg @ Wa + ba); Wa column register-cached from global (L1-hot)
    {
        float acc[4];
        float bav = ba[d];
        #pragma unroll
        for (int u = 0; u < 4; ++u) acc[u] = bav;
        #pragma unroll
        for (int c = 0; c < 32; ++c) {
            float wa = Wa[c * 32 + d];
            #pragma unroll
            for (int u = 0; u < 4; ++u)
                acc[u] += sagg[(i0 + u * 8) * HH + c] * wa;
        }
        #pragma unroll
        for (int u = 0; u < 4; ++u)
            sagg2[(i0 + u * 8) * HH + d] = fmaxf(acc[u], 0.f);
    }
    __syncthreads();

    // upd = relu(h @ Wu[:32] + agg2 @ Wu[32:] + bu)
    {
        float acc[4];
        float buv = bu[d];
        #pragma unroll
        for (int u = 0; u < 4; ++u) acc[u] = buv;
        #pragma unroll
        for (int c = 0; c < 32; ++c) {
            float wh = Wu[c * 32 + d];
            float wg = Wu[(32 + c) * 32 + d];
            #pragma unroll
            for (int u = 0; u < 4; ++u) {
                int i = i0 + u * 8;
                acc[u] += sh[i * HH + c] * wh + sagg2[i * HH + c] * wg;
            }
        }
        #pragma unroll
        for (int u = 0; u < 4; ++u)
            supd[(i0 + u * 8) * HH + d] = fmaxf(acc[u], 0.f);
    }
    __syncthreads();

    // dec = upd @ Wd + bd; out[n,t,:] = x[n,6+t,:] + dec
    if (tid < 128) {
        int i = tid >> 2, d4 = tid & 3;
        int n = ib * 32 + i;
        float a = bd[d4];
        #pragma unroll
        for (int c = 0; c < 32; ++c)
            a += supd[i * HH + c] * Wd[c * 4 + d4];
        out[n * (TP * 4) + t * 4 + d4] = x[n * (TT * 4) + (6 + t) * 4 + d4] + a;
    }
}

extern "C" void kernel_launch(void* const* d_in, const int* in_sizes, int n_in,
                              void* d_out, int out_size, void* d_ws, size_t ws_size,
                              hipStream_t stream) {
    const float* x  = (const float*)d_in[0];
    const float* w1 = (const float*)d_in[1];
    const float* b1 = (const float*)d_in[2];
    const float* w2 = (const float*)d_in[3];
    const float* b2 = (const float*)d_in[4];
    const float* w3 = (const float*)d_in[5];
    const float* b3 = (const float*)d_in[6];
    const float* We = (const float*)d_in[7];
    const float* be = (const float*)d_in[8];
    const float* Wa = (const float*)d_in[9];
    const float* ba = (const float*)d_in[10];
    const float* Wu = (const float*)d_in[11];
    const float* bu = (const float*)d_in[12];
    const float* Wd = (const float*)d_in[13];
    const float* bd = (const float*)d_in[14];

    float* ws   = (float*)d_ws;
    float* h_g  = ws;                      // 94*128*32
    float* ej_g = ws + TP * NN * HH;       // 94*128*32
    float* ei_g = ws + 2 * TP * NN * HH;   // 94*128*32

    k_conv<<<dim3(NN, 2), 256, 0, stream>>>(x, w1, b1, w2, b2, w3, b3, We,
                                            h_g, ej_g, ei_g);
    k_agg<<<dim3(TP, 4), 256, 0, stream>>>(x, h_g, ej_g, ei_g,
                                           be, Wa, ba, Wu, bu, Wd, bd,
                                           (float*)d_out);
}